// Round 24
// baseline (153.593 us; speedup 1.0000x reference)
//
#include <hip/hip_runtime.h>
#include <hip/hip_bf16.h>
#include <math.h>

#define HEADS 8
#define DIMH 64
#define NPIX 1024
#define BATCH 16
#define CIN 512
#define HIDDEN 512
#define OQKV 1536

typedef __attribute__((ext_vector_type(8))) short v8s;   // 8 x bf16
typedef __attribute__((ext_vector_type(4))) float v4f;
typedef __attribute__((ext_vector_type(4))) int v4i;

#define MFMA16(a, b, c) __builtin_amdgcn_mfma_f32_16x16x32_bf16(a, b, c, 0, 0, 0)

__device__ inline unsigned pkbf(float lo, float hi) {
    unsigned r;
    asm("v_cvt_pk_bf16_f32 %0, %1, %2" : "=v"(r) : "v"(lo), "v"(hi));
    return r;
}
__device__ inline ushort bf16u(float f) {
    __hip_bfloat16 h = __float2bfloat16(f);
    return *(ushort*)&h;
}
__device__ inline float exp2i(float x) {      // v_exp_f32 is 2^x on gfx950
    float r;
    asm("v_exp_f32 %0, %1" : "=v"(r) : "v"(x));
    return r;
}
// async global->LDS DMA: 64 lanes x 16B; LDS dest = uniform base + lane*16
__device__ inline void gload16(const ushort* g, ushort* l) {
    __builtin_amdgcn_global_load_lds(
        (const __attribute__((address_space(1))) void*)g,
        (__attribute__((address_space(3))) void*)l, 16, 0, 0);
}

#define INVLN2 1.44269504088896f
#define BIAS2  12.2629078475662f   /* 8.5/ln2 ; |s|<=8.07 so arg in (-24,-0.6) */

// ---------------------------------------------------------------------------
// Kernel 1 (fused prep): blocks [0,2048) = xT 64x64 tile transpose;
// [2048,4096) = wnorm row; [4096,4104) = memkv per-head prep.
// mem V pre-normalized (proven R15); mem K raw + msk scale.
// ---------------------------------------------------------------------------
__global__ __launch_bounds__(256) void prep_fused(
    const float* __restrict__ x,
    const float* __restrict__ wq, const float* __restrict__ wo,
    const float* __restrict__ mem_kv,
    ushort* __restrict__ Xt, ushort* __restrict__ wn,
    __hip_bfloat16* __restrict__ mk, __hip_bfloat16* __restrict__ mv,
    float* __restrict__ msk)
{
    int bid = blockIdx.x;
    if (bid < 2048) {
        // ---- xT: x [b][c][p] f32 -> Xt [b][p][c] bf16 ----
        int b = bid >> 7, rem = bid & 127;
        int c0 = (rem >> 4) * 64, p0 = (rem & 15) * 64;
        __shared__ ushort lds[64][72];
        int tid = threadIdx.x;
        int cl = tid >> 2;
        int pl = (tid & 3) * 16;
        const float* src = x + ((size_t)b * CIN + c0 + cl) * NPIX + p0 + pl;
        #pragma unroll
        for (int j = 0; j < 4; j++) {
            float4 v = *(const float4*)(src + j * 4);
            lds[cl][pl + j * 4 + 0] = bf16u(v.x);
            lds[cl][pl + j * 4 + 1] = bf16u(v.y);
            lds[cl][pl + j * 4 + 2] = bf16u(v.z);
            lds[cl][pl + j * 4 + 3] = bf16u(v.w);
        }
        __syncthreads();
        int pw = tid >> 2;
        int cs = (tid & 3) * 16;
        union { ushort u[16]; uint4 q[2]; } tmp;
        #pragma unroll
        for (int j = 0; j < 16; j++) tmp.u[j] = lds[cs + j][pw];
        ushort* dst = Xt + ((size_t)b * NPIX + p0 + pw) * CIN + c0 + cs;
        *(uint4*)(dst) = tmp.q[0];
        *(uint4*)(dst + 8) = tmp.q[1];
    } else if (bid < 4096) {
        // ---- wnorm: Karras weight norm -> bf16 ----
        int row = bid - 2048;
        const float* src = (row < OQKV) ? (wq + (size_t)row * CIN)
                                        : (wo + (size_t)(row - OQKV) * CIN);
        int t = threadIdx.x;
        float v0 = src[t];
        float v1 = src[t + 256];
        float ss = v0 * v0 + v1 * v1;
        #pragma unroll
        for (int off = 32; off >= 1; off >>= 1) ss += __shfl_xor(ss, off);
        __shared__ float red[4];
        if ((t & 63) == 0) red[t >> 6] = ss;
        __syncthreads();
        float total = red[0] + red[1] + red[2] + red[3];
        const float RSQRT512 = 0.044194173824159216f;
        const float SQRT512  = 22.627416997969522f;
        float scale = 1.0f / ((1e-4f + sqrtf(total) * RSQRT512) * SQRT512);
        ushort* dst = wn + (size_t)row * CIN;
        dst[t] = bf16u(v0 * scale);
        dst[t + 256] = bf16u(v1 * scale);
    } else {
        // ---- memkv prep (wave 0 only) ----
        if (threadIdx.x < 64) {
            int h = bid - 4096;
            int lane = threadIdx.x;
            #pragma unroll
            for (int m = 0; m < 4; m++) {
                float kvv = mem_kv[((size_t)h * 4 + m) * 64 + lane];
                float vvv = mem_kv[((size_t)(HEADS + h) * 4 + m) * 64 + lane];
                float ssk = kvv * kvv, ssv = vvv * vvv;
                #pragma unroll
                for (int off = 32; off >= 1; off >>= 1) {
                    ssk += __shfl_xor(ssk, off);
                    ssv += __shfl_xor(ssv, off);
                }
                float sck = 8.0f / fmaxf(sqrtf(ssk), 1e-4f);
                float scv = 8.0f / fmaxf(sqrtf(ssv), 1e-4f);
                mk[((size_t)h * 16 + m) * 64 + lane] = __float2bfloat16(kvv);
                mv[((size_t)h * 64 + lane) * 32 + m] = __float2bfloat16(vvv * scv);
                if (lane == 0) { msk[h * 16 + m] = sck; }
            }
            #pragma unroll
            for (int m = 4; m < 16; m++)
                mk[((size_t)h * 16 + m) * 64 + lane] = __float2bfloat16(0.f);
            #pragma unroll
            for (int m = 4; m < 32; m++)
                mv[((size_t)h * 64 + lane) * 32 + m] = __float2bfloat16(0.f);
            if (lane >= 4 && lane < 16) msk[h * 16 + lane] = 0.f;
        }
    }
}

// ---------------------------------------------------------------------------
// Kernel 2 (fused qkv GEMM, global_load_lds staging — R14..R16-proven).
// K and V pre-normalized into stores; Q raw + qsA.
// ---------------------------------------------------------------------------
__global__ __launch_bounds__(256) void gemm_qkv_mfma(
    const ushort* __restrict__ Wall,  // wn rows [0,2048)
    const ushort* __restrict__ Xt,    // [B][1024][512]
    ushort* __restrict__ Qb, ushort* __restrict__ Kb, ushort* __restrict__ Vb,
    float* __restrict__ qsA)
{
    int bid = blockIdx.x;
    int xcd = bid & 7;
    int rest = bid >> 3;        // 0..191
    int bh2 = rest / 96;        // 0,1
    int r = rest - bh2 * 96;    // 0..95
    int b = xcd + (bh2 << 3);   // batch, pinned to XCD = b&7
    int yy = r % 12;
    int pp = r / 12;            // 0..7

    int p0 = pp * 128;
    int isV = (yy >= 8) ? 1 : 0;
    int o0 = (isV ? (yy - 8) : yy) * 128;
    const ushort* Wsrc = Wall + (isV ? (size_t)1024 * CIN : 0);

    int tid = threadIdx.x;
    int wave = tid >> 6, lane = tid & 63;
    int wy = wave >> 1, wx = wave & 1;
    int col = lane & 15, lg = lane >> 4;
    int pw = p0 + wx * 64;
    int ow = o0 + wy * 64;

    __shared__ __align__(16) ushort sW[128 * 64];   // 16KB
    __shared__ __align__(16) ushort sX[128 * 64];   // 16KB

    int rIn = lane >> 3;                 // 0..7
    int chS = (lane & 7) ^ rIn;          // swizzled source chunk
    int rowStage = wave * 32 + rIn;
    const ushort* gW = Wsrc + (size_t)(o0 + rowStage) * CIN + chS * 8;
    const ushort* gX = Xt + ((size_t)b * NPIX + p0 + rowStage) * CIN + chS * 8;

    v4f acc[4][4];
    #pragma unroll
    for (int i = 0; i < 4; i++)
        #pragma unroll
        for (int j = 0; j < 4; j++) acc[i][j] = (v4f){0.f, 0.f, 0.f, 0.f};

    const ushort* sA = isV ? sX : sW;
    const ushort* sB = isV ? sW : sX;
    int rowA = (isV ? wx : wy) * 64 + col;
    int rowB = (isV ? wy : wx) * 64 + col;
    int c7 = col & 7;

    #pragma unroll 1
    for (int c0 = 0; c0 < CIN; c0 += 64) {
        #pragma unroll
        for (int j = 0; j < 4; j++) {
            gload16(gW + (size_t)j * 8 * CIN + c0, &sW[(wave * 4 + j) * 512]);
            gload16(gX + (size_t)j * 8 * CIN + c0, &sX[(wave * 4 + j) * 512]);
        }
        __syncthreads();
        #pragma unroll
        for (int hh = 0; hh < 2; hh++) {
            int ch = (hh * 4 + lg) ^ c7;
            v8s af[4], bf[4];
            #pragma unroll
            for (int i = 0; i < 4; i++) {
                af[i] = *(const v8s*)&sA[(rowA + i * 16) * 64 + ch * 8];
                bf[i] = *(const v8s*)&sB[(rowB + i * 16) * 64 + ch * 8];
            }
            #pragma unroll
            for (int i = 0; i < 4; i++)
                #pragma unroll
                for (int j = 0; j < 4; j++)
                    acc[i][j] = MFMA16(af[i], bf[j], acc[i][j]);
        }
        __syncthreads();
    }

    if (!isV) {
        // ---------------- Q/K epilogue (acc[dt][pt]) ----------------
        int part = ow >> 9;              // 0 = q, 1 = k
        int h = (ow >> 6) & 7;
        int bh = b * HEADS + h;

        float ssq[4];
        #pragma unroll
        for (int pt = 0; pt < 4; pt++) {
            float s = 0.f;
            #pragma unroll
            for (int dt = 0; dt < 4; dt++)
                #pragma unroll
                for (int r2 = 0; r2 < 4; r2++) s += acc[dt][pt][r2] * acc[dt][pt][r2];
            s += __shfl_xor(s, 16);
            s += __shfl_xor(s, 32);
            ssq[pt] = s;
        }
        if (part == 0) {
            if (lg == 0) {
                #pragma unroll
                for (int pt = 0; pt < 4; pt++)
                    qsA[(size_t)bh * NPIX + pw + pt * 16 + col] =
                        1.0f / fmaxf(sqrtf(ssq[pt]), 1e-4f);
            }
            ushort* dst = Qb + (size_t)bh * NPIX * DIMH;
            #pragma unroll
            for (int pt = 0; pt < 4; pt++) {
                int p = pw + pt * 16 + col;
                #pragma unroll
                for (int dt = 0; dt < 4; dt++) {
                    uint2 uu;
                    uu.x = pkbf(acc[dt][pt][0], acc[dt][pt][1]);
                    uu.y = pkbf(acc[dt][pt][2], acc[dt][pt][3]);
                    *(uint2*)(dst + (size_t)p * DIMH + dt * 16 + 4 * lg) = uu;
                }
            }
        } else {
            float scl[4];
            #pragma unroll
            for (int pt = 0; pt < 4; pt++)
                scl[pt] = 8.0f / fmaxf(sqrtf(ssq[pt]), 1e-4f);
            ushort* dst = Kb + (size_t)bh * NPIX * DIMH;
            #pragma unroll
            for (int pt = 0; pt < 4; pt++) {
                int p = pw + pt * 16 + col;
                #pragma unroll
                for (int dt = 0; dt < 4; dt++) {
                    uint2 uu;
                    uu.x = pkbf(acc[dt][pt][0] * scl[pt], acc[dt][pt][1] * scl[pt]);
                    uu.y = pkbf(acc[dt][pt][2] * scl[pt], acc[dt][pt][3] * scl[pt]);
                    *(uint2*)(dst + (size_t)p * DIMH + dt * 16 + 4 * lg) = uu;
                }
            }
        }
    } else {
        // ---------------- V epilogue: fold Vn = 8v/||v|| (proven R15) ------
        int h = (ow >> 6) & 7;
        int bh = b * HEADS + h;

        float scl[4][4];
        #pragma unroll
        for (int pt = 0; pt < 4; pt++) {
            #pragma unroll
            for (int r2 = 0; r2 < 4; r2++) {
                float s = acc[pt][0][r2] * acc[pt][0][r2] + acc[pt][1][r2] * acc[pt][1][r2]
                        + acc[pt][2][r2] * acc[pt][2][r2] + acc[pt][3][r2] * acc[pt][3][r2];
                s += __shfl_xor(s, 1);
                s += __shfl_xor(s, 2);
                s += __shfl_xor(s, 4);
                s += __shfl_xor(s, 8);
                scl[pt][r2] = 8.0f / fmaxf(sqrtf(s), 1e-4f);
            }
        }
        #pragma unroll
        for (int ot = 0; ot < 4; ot++) {
            int d = ot * 16 + col;
            #pragma unroll
            for (int pt = 0; pt < 4; pt++) {
                uint2 uu;
                uu.x = pkbf(acc[pt][ot][0] * scl[pt][0], acc[pt][ot][1] * scl[pt][1]);
                uu.y = pkbf(acc[pt][ot][2] * scl[pt][2], acc[pt][ot][3] * scl[pt][3]);
                *(uint2*)(Vb + ((size_t)bh * DIMH + d) * NPIX + pw + pt * 16 + 4 * lg) = uu;
            }
        }
    }
}

// ---------------------------------------------------------------------------
// Kernel 3: MFMA flash attention, LDS-staged K/V (R20 body) at 1 q-tile/
// wave: q0 = qb*64 + wave*16, grid 2048 (16 qb x 128 bh; XCD pinning holds
// since bid%8 == bh%8). Continues the R23 occupancy trend: per-wave state
// drops ~28 more regs (qf 8, o_ 16) -> HW can host 5-6 blocks/CU.
// ---------------------------------------------------------------------------
__global__ __launch_bounds__(256, 2) void attn_mfma_kernel(
    const __hip_bfloat16* __restrict__ Qb,
    const __hip_bfloat16* __restrict__ Kb,
    const __hip_bfloat16* __restrict__ Vb,
    const float* __restrict__ qsA,
    const __hip_bfloat16* __restrict__ mk, const __hip_bfloat16* __restrict__ mv,
    const float* __restrict__ msk,
    ushort* __restrict__ attT)
{
    int bid = blockIdx.x;
    int bh = bid & 127;
    int qb = bid >> 7;           // 0..15
    int b = bh >> 3, h = bh & 7;
    int wave = threadIdx.x >> 6, lane = threadIdx.x & 63;
    int col = lane & 15, lg = lane >> 4;
    int q0 = qb * 64 + wave * 16;

    __shared__ __align__(16) ushort sK[2][64 * 64];   // 8KB each
    __shared__ __align__(16) ushort sV[2][64 * 64];   // 8KB each

    const ushort* Kg = (const ushort*)Kb + (size_t)bh * NPIX * DIMH;
    const ushort* Vg = (const ushort*)Vb + (size_t)bh * DIMH * NPIX;
    const __hip_bfloat16* Qbase = Qb + ((size_t)bh * NPIX + q0) * DIMH;

    int rIn = lane >> 3;                 // 0..7
    int chS = (lane & 7) ^ rIn;          // pre-swizzled source granule

    v8s qf[2];
    float myqs;
    #pragma unroll
    for (int dh = 0; dh < 2; dh++)
        qf[dh] = *(const v8s*)(Qbase + col * DIMH + dh * 32 + 8 * lg);
    myqs = qsA[(size_t)bh * NPIX + q0 + col] * INVLN2;

    v4f o_[4];
    #pragma unroll
    for (int dt = 0; dt < 4; dt++) o_[dt] = (v4f){0.f, 0.f, 0.f, 0.f};
    float l_ = 0.f;

    int srcA = ((lg & 1) << 5) + col;
    int srcB = srcA + 16;
    bool hig = (lg >= 2);

    // ---- mem-kv tile (rows 0..3 valid, on lg==0 lanes; mv pre-scaled) ----
    {
        const __hip_bfloat16* mkh = mk + (size_t)h * 16 * DIMH;
        v8s kf0 = *(const v8s*)(mkh + col * DIMH + 8 * lg);
        v8s kf1 = *(const v8s*)(mkh + col * DIMH + 32 + 8 * lg);
        v8s vfm[4];
        #pragma unroll
        for (int dt = 0; dt < 4; dt++)
            vfm[dt] = *(const v8s*)(mv + ((size_t)h * DIMH + dt * 16 + col) * 32 + 8 * lg);
        float4 ksm = *(const float4*)&msk[h * 16 + 4 * lg];
        float ksr[4] = {ksm.x, ksm.y, ksm.z, ksm.w};

        v4f c0 = (v4f){0.f, 0.f, 0.f, 0.f};
        c0 = MFMA16(kf0, qf[0], c0);
        c0 = MFMA16(kf1, qf[1], c0);
        float p0[4];
        #pragma unroll
        for (int r = 0; r < 4; r++) {
            float t = __builtin_fmaf(c0[r], myqs * ksr[r], -BIAS2);
            p0[r] = (lg == 0) ? exp2i(t) : 0.f;
            l_ += p0[r];
        }
        unsigned A0 = pkbf(p0[0], p0[1]);
        unsigned A1 = pkbf(p0[2], p0[3]);
        int a0 = __shfl((int)A0, srcA), a1 = __shfl((int)A1, srcA);
        int a2 = __shfl((int)A0, srcB), a3 = __shfl((int)A1, srcB);
        v4i w;
        w.x = hig ? 0 : a0; w.y = hig ? 0 : a1;
        w.z = hig ? 0 : a2; w.w = hig ? 0 : a3;
        v8s pf = __builtin_bit_cast(v8s, w);
        #pragma unroll
        for (int dt = 0; dt < 4; dt++)
            o_[dt] = MFMA16(vfm[dt], pf, o_[dt]);
    }

    // ---- STAGE: wave w covers 16 rows (2 calls x 8 rows) of K and V ------
    #define STAGE(cur, kk) { \
        _Pragma("unroll") \
        for (int j = 0; j < 2; j++) { \
            gload16(Kg + ((size_t)(kk) + wave * 16 + j * 8 + rIn) * 64 + chS * 8, \
                    &sK[cur][wave * 1024 + j * 512]); \
            gload16(Vg + ((size_t)(wave * 16 + j * 8 + rIn)) * 1024 + (kk) + chS * 8, \
                    &sV[cur][wave * 1024 + j * 512]); \
        } }

    // ---- COMPUTE one 32-k-row half (ks=0/1) from LDS buffer `cur` --------
    #define COMPUTE_LDS(cur, ks) { \
        v8s kf[4], vf[4]; \
        int rk0 = (ks) * 32 + col, rk1 = rk0 + 16; \
        int sw = col & 7; \
        kf[0] = *(const v8s*)&sK[cur][rk0 * 64 + ((lg    ) ^ sw) * 8]; \
        kf[1] = *(const v8s*)&sK[cur][rk0 * 64 + ((lg + 4) ^ sw) * 8]; \
        kf[2] = *(const v8s*)&sK[cur][rk1 * 64 + ((lg    ) ^ sw) * 8]; \
        kf[3] = *(const v8s*)&sK[cur][rk1 * 64 + ((lg + 4) ^ sw) * 8]; \
        _Pragma("unroll") \
        for (int dt = 0; dt < 4; dt++) \
            vf[dt] = *(const v8s*)&sV[cur][(dt * 16 + col) * 64 + (((ks) * 4 + lg) ^ sw) * 8]; \
        v4f c0 = (v4f){0.f, 0.f, 0.f, 0.f}; \
        v4f c1 = (v4f){0.f, 0.f, 0.f, 0.f}; \
        __builtin_amdgcn_s_setprio(1); \
        c0 = MFMA16(kf[0], qf[0], c0); \
        c0 = MFMA16(kf[1], qf[1], c0); \
        c1 = MFMA16(kf[2], qf[0], c1); \
        c1 = MFMA16(kf[3], qf[1], c1); \
        __builtin_amdgcn_s_setprio(0); \
        float p0[4], p1[4]; \
        _Pragma("unroll") \
        for (int r = 0; r < 4; r++) { \
            p0[r] = exp2i(__builtin_fmaf(c0[r], myqs, -BIAS2)); \
            p1[r] = exp2i(__builtin_fmaf(c1[r], myqs, -BIAS2)); \
            l_ += p0[r] + p1[r]; \
        } \
        unsigned A0 = pkbf(p0[0], p0[1]); \
        unsigned A1 = pkbf(p0[2], p0[3]); \
        unsigned B0 = pkbf(p1[0], p1[1]); \
        unsigned B1 = pkbf(p1[2], p1[3]); \
        int a0 = __shfl((int)A0, srcA), a1 = __shfl((int)A1, srcA); \
        int a2 = __shfl((int)A0, srcB), a3 = __shfl((int)A1, srcB); \
        int b0 = __shfl((int)B0, srcA), b1 = __shfl((int)B1, srcA); \
        int b2 = __shfl((int)B0, srcB), b3 = __shfl((int)B1, srcB); \
        v4i w; \
        w.x = hig ? b0 : a0; w.y = hig ? b1 : a1; \
        w.z = hig ? b2 : a2; w.w = hig ? b3 : a3; \
        v8s pf = __builtin_bit_cast(v8s, w); \
        __builtin_amdgcn_s_setprio(1); \
        _Pragma("unroll") \
        for (int dt = 0; dt < 4; dt++) \
            o_[dt] = MFMA16(vf[dt], pf, o_[dt]); \
        __builtin_amdgcn_s_setprio(0); \
    }

    // ---- main loop: 16 tiles of 64 k-rows, LDS double-buffered -----------
    int cur = 0;
    STAGE(0, 0);
    __syncthreads();
    #pragma unroll 1
    for (int t = 0; t < 16; t++) {
        if (t < 15) STAGE(cur ^ 1, (t + 1) * 64);   // async, lands by barrier
        COMPUTE_LDS(cur, 0);
        COMPUTE_LDS(cur, 1);
        __syncthreads();    // drains vmcnt: next buffer ready; reads of cur done
        cur ^= 1;
    }

    // ---- epilogue: reduce per-lane l across lane-groups once, write attT ----
    {
        float l = l_;
        l += __shfl_xor(l, 16);
        l += __shfl_xor(l, 32);
        float invl = 1.0f / l;
        ushort* at = attT + ((size_t)(b * NPIX + q0 + col)) * HIDDEN + h * DIMH;
        #pragma unroll
        for (int dt = 0; dt < 4; dt++) {
            uint2 uu;
            uu.x = pkbf(o_[dt][0] * invl, o_[dt][1] * invl);
            uu.y = pkbf(o_[dt][2] * invl, o_[dt][3] * invl);
            *(uint2*)(at + dt * 16 + 4 * lg) = uu;
        }
    }
    #undef STAGE
    #undef COMPUTE_LDS
}

// ---------------------------------------------------------------------------
// Kernel 4: out-proj GEMM with global_load_lds staging (R15-proven).
// ---------------------------------------------------------------------------
__global__ __launch_bounds__(256) void gemm_out_mfma(
    const ushort* __restrict__ Wo,
    const ushort* __restrict__ attT,
    const float* __restrict__ x, float* __restrict__ out)
{
    int b = blockIdx.z;
    int o0 = blockIdx.y * 128;
    int p0 = blockIdx.x * 128;
    int tid = threadIdx.x;
    int wave = tid >> 6, lane = tid & 63;
    int wy = wave >> 1, wx = wave & 1;
    int col = lane & 15, lg = lane >> 4;
    int ow = o0 + wy * 64, pw = p0 + wx * 64;

    __shared__ __align__(16) ushort sAa[128 * 64];  // attT rows
    __shared__ __align__(16) ushort sBb[128 * 64];  // Wo rows

    int rIn = lane >> 3;
    int chS = (lane & 7) ^ rIn;
    int rowStage = wave * 32 + rIn;
    const ushort* gA = attT + ((size_t)b * NPIX + p0 + rowStage) * HIDDEN + chS * 8;
    const ushort* gB = Wo + (size_t)(o0 + rowStage) * HIDDEN + chS * 8;

    v4f acc[4][4];   // [pt][ot]
    #pragma unroll
    for (int i = 0; i < 4; i++)
        #pragma unroll
        for (int j = 0; j < 4; j++) acc[i][j] = (v4f){0.f, 0.f, 0.f, 0.f};

    int rowA = wx * 64 + col;   // p side
    int rowB = wy * 64 + col;   // o side
    int c7 = col & 7;

    #pragma unroll 1
    for (int c0 = 0; c0 < HIDDEN; c0 += 64) {
        #pragma unroll
        for (int j = 0; j < 4; j++) {
            gload16(gA + (size_t)j * 8 * HIDDEN + c0, &sAa[(wave * 4 + j) * 512]);
            gload16(gB + (size_t)j * 8 * HIDDEN + c0, &sBb[(wave * 4 + j) * 512]);
        }
        __syncthreads();
        #pragma unroll
        for (int hh = 0; hh < 2; hh++) {
            int ch = (hh * 4 + lg) ^ c7;
            v8s af[4], bf[4];
            #pragma unroll
            for (int i = 0; i < 4; i++) {
                af[i] = *(const v8s*)&sAa[(rowA + i * 16) * 64 + ch * 8];
                bf[i] = *(const v8s*)&sBb[(rowB + i * 16) * 64 + ch * 8];
            }
            #pragma unroll
            for (int i = 0; i < 4; i++)
                #pragma unroll
                for (int j = 0; j < 4; j++)
                    acc[i][j] = MFMA16(af[i], bf[j], acc[i][j]);
        }
        __syncthreads();
    }

    const float INV_DEN = 1.3130643285972254f;
    #pragma unroll
    for (int pt = 0; pt < 4; pt++) {
        #pragma unroll
        for (int ot = 0; ot < 4; ot++) {
            size_t base = ((size_t)b * HIDDEN + ow + ot * 16 + col) * NPIX
                        + pw + pt * 16 + 4 * lg;
            float4 res = *(const float4*)&x[base];
            float4 y;
            y.x = (acc[pt][ot][0] * 0.7f + res.x * 0.3f) * INV_DEN;
            y.y = (acc[pt][ot][1] * 0.7f + res.y * 0.3f) * INV_DEN;
            y.z = (acc[pt][ot][2] * 0.7f + res.z * 0.3f) * INV_DEN;
            y.w = (acc[pt][ot][3] * 0.7f + res.w * 0.3f) * INV_DEN;
            *(float4*)&out[base] = y;
        }
    }
}

// ---------------------------------------------------------------------------
extern "C" void kernel_launch(void* const* d_in, const int* in_sizes, int n_in,
                              void* d_out, int out_size, void* d_ws, size_t ws_size,
                              hipStream_t stream)
{
    const float* x      = (const float*)d_in[0];
    const float* w_qkv  = (const float*)d_in[1];
    const float* w_out  = (const float*)d_in[2];
    const float* mem_kv = (const float*)d_in[3];
    float* out = (float*)d_out;

    char* ws = (char*)d_ws;
    ushort* wnB = (ushort*)ws; ws += (size_t)2048 * CIN * 2;
    ushort* Xt  = (ushort*)ws; ws += (size_t)BATCH * NPIX * CIN * 2;
    ushort* Qb  = (ushort*)ws; ws += (size_t)BATCH * HEADS * NPIX * DIMH * 2;
    ushort* Kb  = (ushort*)ws; ws += (size_t)BATCH * HEADS * NPIX * DIMH * 2;
    ushort* Vb  = (ushort*)ws; ws += (size_t)BATCH * HEADS * NPIX * DIMH * 2;
    ushort* attT = (ushort*)ws; ws += (size_t)BATCH * NPIX * HIDDEN * 2;
    float* qsA = (float*)ws;  ws += (size_t)BATCH * HEADS * NPIX * 4;
    float* msk = (float*)ws;  ws += 8 * 16 * 4;
    __hip_bfloat16* mk = (__hip_bfloat16*)ws; ws += (size_t)8 * 16 * 64 * 2;
    __hip_bfloat16* mv = (__hip_bfloat16*)ws; ws += (size_t)8 * 64 * 32 * 2;

    prep_fused<<<4104, 256, 0, stream>>>(
        x, w_qkv, w_out, mem_kv, Xt, wnB, mk, mv, msk);

    gemm_qkv_mfma<<<1536, 256, 0, stream>>>(
        wnB, Xt, Qb, Kb, Vb, qsA);

    attn_mfma_kernel<<<2048, 256, 0, stream>>>(
        (const __hip_bfloat16*)Qb, (const __hip_bfloat16*)Kb,
        (const __hip_bfloat16*)Vb, qsA, mk, mv, msk, attT);

    gemm_out_mfma<<<dim3(8, 4, BATCH), 256, 0, stream>>>(
        wnB + (size_t)OQKV * CIN, attT, x, out);
}

// Round 25
// 141.029 us; speedup vs baseline: 1.0891x; 1.0891x over previous
//
#include <hip/hip_runtime.h>
#include <hip/hip_bf16.h>
#include <math.h>

#define HEADS 8
#define DIMH 64
#define NPIX 1024
#define BATCH 16
#define CIN 512
#define HIDDEN 512
#define OQKV 1536

typedef __attribute__((ext_vector_type(8))) short v8s;   // 8 x bf16
typedef __attribute__((ext_vector_type(4))) float v4f;
typedef __attribute__((ext_vector_type(4))) int v4i;

#define MFMA16(a, b, c) __builtin_amdgcn_mfma_f32_16x16x32_bf16(a, b, c, 0, 0, 0)

__device__ inline unsigned pkbf(float lo, float hi) {
    unsigned r;
    asm("v_cvt_pk_bf16_f32 %0, %1, %2" : "=v"(r) : "v"(lo), "v"(hi));
    return r;
}
__device__ inline ushort bf16u(float f) {
    __hip_bfloat16 h = __float2bfloat16(f);
    return *(ushort*)&h;
}
__device__ inline float exp2i(float x) {      // v_exp_f32 is 2^x on gfx950
    float r;
    asm("v_exp_f32 %0, %1" : "=v"(r) : "v"(x));
    return r;
}
// async global->LDS DMA: 64 lanes x 16B; LDS dest = uniform base + lane*16
__device__ inline void gload16(const ushort* g, ushort* l) {
    __builtin_amdgcn_global_load_lds(
        (const __attribute__((address_space(1))) void*)g,
        (__attribute__((address_space(3))) void*)l, 16, 0, 0);
}

#define INVLN2 1.44269504088896f
#define BIAS2  12.2629078475662f   /* 8.5/ln2 ; |s|<=8.07 so arg in (-24,-0.6) */

// ---------------------------------------------------------------------------
// Kernel 1 (fused prep): blocks [0,2048) = xT 64x64 tile transpose;
// [2048,4096) = wnorm row; [4096,4104) = memkv per-head prep.
// mem V pre-normalized (proven R15); mem K raw + msk scale.
// ---------------------------------------------------------------------------
__global__ __launch_bounds__(256) void prep_fused(
    const float* __restrict__ x,
    const float* __restrict__ wq, const float* __restrict__ wo,
    const float* __restrict__ mem_kv,
    ushort* __restrict__ Xt, ushort* __restrict__ wn,
    __hip_bfloat16* __restrict__ mk, __hip_bfloat16* __restrict__ mv,
    float* __restrict__ msk)
{
    int bid = blockIdx.x;
    if (bid < 2048) {
        // ---- xT: x [b][c][p] f32 -> Xt [b][p][c] bf16 ----
        int b = bid >> 7, rem = bid & 127;
        int c0 = (rem >> 4) * 64, p0 = (rem & 15) * 64;
        __shared__ ushort lds[64][72];
        int tid = threadIdx.x;
        int cl = tid >> 2;
        int pl = (tid & 3) * 16;
        const float* src = x + ((size_t)b * CIN + c0 + cl) * NPIX + p0 + pl;
        #pragma unroll
        for (int j = 0; j < 4; j++) {
            float4 v = *(const float4*)(src + j * 4);
            lds[cl][pl + j * 4 + 0] = bf16u(v.x);
            lds[cl][pl + j * 4 + 1] = bf16u(v.y);
            lds[cl][pl + j * 4 + 2] = bf16u(v.z);
            lds[cl][pl + j * 4 + 3] = bf16u(v.w);
        }
        __syncthreads();
        int pw = tid >> 2;
        int cs = (tid & 3) * 16;
        union { ushort u[16]; uint4 q[2]; } tmp;
        #pragma unroll
        for (int j = 0; j < 16; j++) tmp.u[j] = lds[cs + j][pw];
        ushort* dst = Xt + ((size_t)b * NPIX + p0 + pw) * CIN + c0 + cs;
        *(uint4*)(dst) = tmp.q[0];
        *(uint4*)(dst + 8) = tmp.q[1];
    } else if (bid < 4096) {
        // ---- wnorm: Karras weight norm -> bf16 ----
        int row = bid - 2048;
        const float* src = (row < OQKV) ? (wq + (size_t)row * CIN)
                                        : (wo + (size_t)(row - OQKV) * CIN);
        int t = threadIdx.x;
        float v0 = src[t];
        float v1 = src[t + 256];
        float ss = v0 * v0 + v1 * v1;
        #pragma unroll
        for (int off = 32; off >= 1; off >>= 1) ss += __shfl_xor(ss, off);
        __shared__ float red[4];
        if ((t & 63) == 0) red[t >> 6] = ss;
        __syncthreads();
        float total = red[0] + red[1] + red[2] + red[3];
        const float RSQRT512 = 0.044194173824159216f;
        const float SQRT512  = 22.627416997969522f;
        float scale = 1.0f / ((1e-4f + sqrtf(total) * RSQRT512) * SQRT512);
        ushort* dst = wn + (size_t)row * CIN;
        dst[t] = bf16u(v0 * scale);
        dst[t + 256] = bf16u(v1 * scale);
    } else {
        // ---- memkv prep (wave 0 only) ----
        if (threadIdx.x < 64) {
            int h = bid - 4096;
            int lane = threadIdx.x;
            #pragma unroll
            for (int m = 0; m < 4; m++) {
                float kvv = mem_kv[((size_t)h * 4 + m) * 64 + lane];
                float vvv = mem_kv[((size_t)(HEADS + h) * 4 + m) * 64 + lane];
                float ssk = kvv * kvv, ssv = vvv * vvv;
                #pragma unroll
                for (int off = 32; off >= 1; off >>= 1) {
                    ssk += __shfl_xor(ssk, off);
                    ssv += __shfl_xor(ssv, off);
                }
                float sck = 8.0f / fmaxf(sqrtf(ssk), 1e-4f);
                float scv = 8.0f / fmaxf(sqrtf(ssv), 1e-4f);
                mk[((size_t)h * 16 + m) * 64 + lane] = __float2bfloat16(kvv);
                mv[((size_t)h * 64 + lane) * 32 + m] = __float2bfloat16(vvv * scv);
                if (lane == 0) { msk[h * 16 + m] = sck; }
            }
            #pragma unroll
            for (int m = 4; m < 16; m++)
                mk[((size_t)h * 16 + m) * 64 + lane] = __float2bfloat16(0.f);
            #pragma unroll
            for (int m = 4; m < 32; m++)
                mv[((size_t)h * 64 + lane) * 32 + m] = __float2bfloat16(0.f);
            if (lane >= 4 && lane < 16) msk[h * 16 + lane] = 0.f;
        }
    }
}

// ---------------------------------------------------------------------------
// Kernel 2 (fused qkv GEMM, global_load_lds staging — R14..R16-proven).
// K and V pre-normalized into stores; Q raw + qsA.
// ---------------------------------------------------------------------------
__global__ __launch_bounds__(256) void gemm_qkv_mfma(
    const ushort* __restrict__ Wall,  // wn rows [0,2048)
    const ushort* __restrict__ Xt,    // [B][1024][512]
    ushort* __restrict__ Qb, ushort* __restrict__ Kb, ushort* __restrict__ Vb,
    float* __restrict__ qsA)
{
    int bid = blockIdx.x;
    int xcd = bid & 7;
    int rest = bid >> 3;        // 0..191
    int bh2 = rest / 96;        // 0,1
    int r = rest - bh2 * 96;    // 0..95
    int b = xcd + (bh2 << 3);   // batch, pinned to XCD = b&7
    int yy = r % 12;
    int pp = r / 12;            // 0..7

    int p0 = pp * 128;
    int isV = (yy >= 8) ? 1 : 0;
    int o0 = (isV ? (yy - 8) : yy) * 128;
    const ushort* Wsrc = Wall + (isV ? (size_t)1024 * CIN : 0);

    int tid = threadIdx.x;
    int wave = tid >> 6, lane = tid & 63;
    int wy = wave >> 1, wx = wave & 1;
    int col = lane & 15, lg = lane >> 4;
    int pw = p0 + wx * 64;
    int ow = o0 + wy * 64;

    __shared__ __align__(16) ushort sW[128 * 64];   // 16KB
    __shared__ __align__(16) ushort sX[128 * 64];   // 16KB

    int rIn = lane >> 3;                 // 0..7
    int chS = (lane & 7) ^ rIn;          // swizzled source chunk
    int rowStage = wave * 32 + rIn;
    const ushort* gW = Wsrc + (size_t)(o0 + rowStage) * CIN + chS * 8;
    const ushort* gX = Xt + ((size_t)b * NPIX + p0 + rowStage) * CIN + chS * 8;

    v4f acc[4][4];
    #pragma unroll
    for (int i = 0; i < 4; i++)
        #pragma unroll
        for (int j = 0; j < 4; j++) acc[i][j] = (v4f){0.f, 0.f, 0.f, 0.f};

    const ushort* sA = isV ? sX : sW;
    const ushort* sB = isV ? sW : sX;
    int rowA = (isV ? wx : wy) * 64 + col;
    int rowB = (isV ? wy : wx) * 64 + col;
    int c7 = col & 7;

    #pragma unroll 1
    for (int c0 = 0; c0 < CIN; c0 += 64) {
        #pragma unroll
        for (int j = 0; j < 4; j++) {
            gload16(gW + (size_t)j * 8 * CIN + c0, &sW[(wave * 4 + j) * 512]);
            gload16(gX + (size_t)j * 8 * CIN + c0, &sX[(wave * 4 + j) * 512]);
        }
        __syncthreads();
        #pragma unroll
        for (int hh = 0; hh < 2; hh++) {
            int ch = (hh * 4 + lg) ^ c7;
            v8s af[4], bf[4];
            #pragma unroll
            for (int i = 0; i < 4; i++) {
                af[i] = *(const v8s*)&sA[(rowA + i * 16) * 64 + ch * 8];
                bf[i] = *(const v8s*)&sB[(rowB + i * 16) * 64 + ch * 8];
            }
            #pragma unroll
            for (int i = 0; i < 4; i++)
                #pragma unroll
                for (int j = 0; j < 4; j++)
                    acc[i][j] = MFMA16(af[i], bf[j], acc[i][j]);
        }
        __syncthreads();
    }

    if (!isV) {
        // ---------------- Q/K epilogue (acc[dt][pt]) ----------------
        int part = ow >> 9;              // 0 = q, 1 = k
        int h = (ow >> 6) & 7;
        int bh = b * HEADS + h;

        float ssq[4];
        #pragma unroll
        for (int pt = 0; pt < 4; pt++) {
            float s = 0.f;
            #pragma unroll
            for (int dt = 0; dt < 4; dt++)
                #pragma unroll
                for (int r2 = 0; r2 < 4; r2++) s += acc[dt][pt][r2] * acc[dt][pt][r2];
            s += __shfl_xor(s, 16);
            s += __shfl_xor(s, 32);
            ssq[pt] = s;
        }
        if (part == 0) {
            if (lg == 0) {
                #pragma unroll
                for (int pt = 0; pt < 4; pt++)
                    qsA[(size_t)bh * NPIX + pw + pt * 16 + col] =
                        1.0f / fmaxf(sqrtf(ssq[pt]), 1e-4f);
            }
            ushort* dst = Qb + (size_t)bh * NPIX * DIMH;
            #pragma unroll
            for (int pt = 0; pt < 4; pt++) {
                int p = pw + pt * 16 + col;
                #pragma unroll
                for (int dt = 0; dt < 4; dt++) {
                    uint2 uu;
                    uu.x = pkbf(acc[dt][pt][0], acc[dt][pt][1]);
                    uu.y = pkbf(acc[dt][pt][2], acc[dt][pt][3]);
                    *(uint2*)(dst + (size_t)p * DIMH + dt * 16 + 4 * lg) = uu;
                }
            }
        } else {
            float scl[4];
            #pragma unroll
            for (int pt = 0; pt < 4; pt++)
                scl[pt] = 8.0f / fmaxf(sqrtf(ssq[pt]), 1e-4f);
            ushort* dst = Kb + (size_t)bh * NPIX * DIMH;
            #pragma unroll
            for (int pt = 0; pt < 4; pt++) {
                int p = pw + pt * 16 + col;
                #pragma unroll
                for (int dt = 0; dt < 4; dt++) {
                    uint2 uu;
                    uu.x = pkbf(acc[dt][pt][0] * scl[pt], acc[dt][pt][1] * scl[pt]);
                    uu.y = pkbf(acc[dt][pt][2] * scl[pt], acc[dt][pt][3] * scl[pt]);
                    *(uint2*)(dst + (size_t)p * DIMH + dt * 16 + 4 * lg) = uu;
                }
            }
        }
    } else {
        // ---------------- V epilogue: fold Vn = 8v/||v|| (proven R15) ------
        int h = (ow >> 6) & 7;
        int bh = b * HEADS + h;

        float scl[4][4];
        #pragma unroll
        for (int pt = 0; pt < 4; pt++) {
            #pragma unroll
            for (int r2 = 0; r2 < 4; r2++) {
                float s = acc[pt][0][r2] * acc[pt][0][r2] + acc[pt][1][r2] * acc[pt][1][r2]
                        + acc[pt][2][r2] * acc[pt][2][r2] + acc[pt][3][r2] * acc[pt][3][r2];
                s += __shfl_xor(s, 1);
                s += __shfl_xor(s, 2);
                s += __shfl_xor(s, 4);
                s += __shfl_xor(s, 8);
                scl[pt][r2] = 8.0f / fmaxf(sqrtf(s), 1e-4f);
            }
        }
        #pragma unroll
        for (int ot = 0; ot < 4; ot++) {
            int d = ot * 16 + col;
            #pragma unroll
            for (int pt = 0; pt < 4; pt++) {
                uint2 uu;
                uu.x = pkbf(acc[pt][ot][0] * scl[pt][0], acc[pt][ot][1] * scl[pt][1]);
                uu.y = pkbf(acc[pt][ot][2] * scl[pt][2], acc[pt][ot][3] * scl[pt][3]);
                *(uint2*)(Vb + ((size_t)bh * DIMH + d) * NPIX + pw + pt * 16 + 4 * lg) = uu;
            }
        }
    }
}

// ---------------------------------------------------------------------------
// Kernel 3: MFMA flash attention, LDS-staged K/V (best measured config,
// benched twice at 142.0/141.7 us total). 4 q-tiles/wave, grid 512
// (4 qb x 128 bh, XCD-pinned), 64-k-row tiles double-buffered (32KB), ONE
// barrier per tile with STAGE(next) issued before compute, fixed-max
// exp2-fma softmax, K and V pre-normalized, setprio around MFMA clusters.
// ---------------------------------------------------------------------------
__global__ __launch_bounds__(256, 2) void attn_mfma_kernel(
    const __hip_bfloat16* __restrict__ Qb,
    const __hip_bfloat16* __restrict__ Kb,
    const __hip_bfloat16* __restrict__ Vb,
    const float* __restrict__ qsA,
    const __hip_bfloat16* __restrict__ mk, const __hip_bfloat16* __restrict__ mv,
    const float* __restrict__ msk,
    ushort* __restrict__ attT)
{
    int bid = blockIdx.x;
    int bh = bid & 127;
    int qb = bid >> 7;           // 0..3
    int b = bh >> 3, h = bh & 7;
    int wave = threadIdx.x >> 6, lane = threadIdx.x & 63;
    int col = lane & 15, lg = lane >> 4;
    int q0 = qb * 256 + wave * 64;

    __shared__ __align__(16) ushort sK[2][64 * 64];   // 8KB each
    __shared__ __align__(16) ushort sV[2][64 * 64];   // 8KB each

    const ushort* Kg = (const ushort*)Kb + (size_t)bh * NPIX * DIMH;
    const ushort* Vg = (const ushort*)Vb + (size_t)bh * DIMH * NPIX;
    const __hip_bfloat16* Qbase = Qb + ((size_t)bh * NPIX + q0) * DIMH;

    int rIn = lane >> 3;                 // 0..7
    int chS = (lane & 7) ^ rIn;          // pre-swizzled source granule

    v8s qf[4][2];
    float myqs[4];
    #pragma unroll
    for (int qt = 0; qt < 4; qt++) {
        #pragma unroll
        for (int dh = 0; dh < 2; dh++)
            qf[qt][dh] = *(const v8s*)(Qbase + (qt * 16 + col) * DIMH + dh * 32 + 8 * lg);
        myqs[qt] = qsA[(size_t)bh * NPIX + q0 + qt * 16 + col] * INVLN2;
    }

    v4f o_[4][4];
    #pragma unroll
    for (int qt = 0; qt < 4; qt++)
        #pragma unroll
        for (int dt = 0; dt < 4; dt++) o_[qt][dt] = (v4f){0.f, 0.f, 0.f, 0.f};
    float l_[4] = {0.f, 0.f, 0.f, 0.f};

    int srcA = ((lg & 1) << 5) + col;
    int srcB = srcA + 16;
    bool hig = (lg >= 2);

    // ---- mem-kv tile (rows 0..3 valid, on lg==0 lanes; mv pre-scaled) ----
    {
        const __hip_bfloat16* mkh = mk + (size_t)h * 16 * DIMH;
        v8s kf0 = *(const v8s*)(mkh + col * DIMH + 8 * lg);
        v8s kf1 = *(const v8s*)(mkh + col * DIMH + 32 + 8 * lg);
        v8s vfm[4];
        #pragma unroll
        for (int dt = 0; dt < 4; dt++)
            vfm[dt] = *(const v8s*)(mv + ((size_t)h * DIMH + dt * 16 + col) * 32 + 8 * lg);
        float4 ksm = *(const float4*)&msk[h * 16 + 4 * lg];
        float ksr[4] = {ksm.x, ksm.y, ksm.z, ksm.w};

        #pragma unroll
        for (int qt = 0; qt < 4; qt++) {
            v4f c0 = (v4f){0.f, 0.f, 0.f, 0.f};
            c0 = MFMA16(kf0, qf[qt][0], c0);
            c0 = MFMA16(kf1, qf[qt][1], c0);
            float p0[4];
            #pragma unroll
            for (int r = 0; r < 4; r++) {
                float t = __builtin_fmaf(c0[r], myqs[qt] * ksr[r], -BIAS2);
                p0[r] = (lg == 0) ? exp2i(t) : 0.f;
                l_[qt] += p0[r];
            }
            unsigned A0 = pkbf(p0[0], p0[1]);
            unsigned A1 = pkbf(p0[2], p0[3]);
            int a0 = __shfl((int)A0, srcA), a1 = __shfl((int)A1, srcA);
            int a2 = __shfl((int)A0, srcB), a3 = __shfl((int)A1, srcB);
            v4i w;
            w.x = hig ? 0 : a0; w.y = hig ? 0 : a1;
            w.z = hig ? 0 : a2; w.w = hig ? 0 : a3;
            v8s pf = __builtin_bit_cast(v8s, w);
            #pragma unroll
            for (int dt = 0; dt < 4; dt++)
                o_[qt][dt] = MFMA16(vfm[dt], pf, o_[qt][dt]);
        }
    }

    // ---- STAGE: wave w covers 16 rows (2 calls x 8 rows) of K and V ------
    #define STAGE(cur, kk) { \
        _Pragma("unroll") \
        for (int j = 0; j < 2; j++) { \
            gload16(Kg + ((size_t)(kk) + wave * 16 + j * 8 + rIn) * 64 + chS * 8, \
                    &sK[cur][wave * 1024 + j * 512]); \
            gload16(Vg + ((size_t)(wave * 16 + j * 8 + rIn)) * 1024 + (kk) + chS * 8, \
                    &sV[cur][wave * 1024 + j * 512]); \
        } }

    // ---- COMPUTE one 32-k-row half (ks=0/1) from LDS buffer `cur` --------
    #define COMPUTE_LDS(cur, ks) { \
        v8s kf[4], vf[4]; \
        int rk0 = (ks) * 32 + col, rk1 = rk0 + 16; \
        int sw = col & 7; \
        kf[0] = *(const v8s*)&sK[cur][rk0 * 64 + ((lg    ) ^ sw) * 8]; \
        kf[1] = *(const v8s*)&sK[cur][rk0 * 64 + ((lg + 4) ^ sw) * 8]; \
        kf[2] = *(const v8s*)&sK[cur][rk1 * 64 + ((lg    ) ^ sw) * 8]; \
        kf[3] = *(const v8s*)&sK[cur][rk1 * 64 + ((lg + 4) ^ sw) * 8]; \
        _Pragma("unroll") \
        for (int dt = 0; dt < 4; dt++) \
            vf[dt] = *(const v8s*)&sV[cur][(dt * 16 + col) * 64 + (((ks) * 4 + lg) ^ sw) * 8]; \
        _Pragma("unroll") \
        for (int qt = 0; qt < 4; qt++) { \
            v4f c0 = (v4f){0.f, 0.f, 0.f, 0.f}; \
            v4f c1 = (v4f){0.f, 0.f, 0.f, 0.f}; \
            __builtin_amdgcn_s_setprio(1); \
            c0 = MFMA16(kf[0], qf[qt][0], c0); \
            c0 = MFMA16(kf[1], qf[qt][1], c0); \
            c1 = MFMA16(kf[2], qf[qt][0], c1); \
            c1 = MFMA16(kf[3], qf[qt][1], c1); \
            __builtin_amdgcn_s_setprio(0); \
            float p0[4], p1[4]; \
            _Pragma("unroll") \
            for (int r = 0; r < 4; r++) { \
                p0[r] = exp2i(__builtin_fmaf(c0[r], myqs[qt], -BIAS2)); \
                p1[r] = exp2i(__builtin_fmaf(c1[r], myqs[qt], -BIAS2)); \
                l_[qt] += p0[r] + p1[r]; \
            } \
            unsigned A0 = pkbf(p0[0], p0[1]); \
            unsigned A1 = pkbf(p0[2], p0[3]); \
            unsigned B0 = pkbf(p1[0], p1[1]); \
            unsigned B1 = pkbf(p1[2], p1[3]); \
            int a0 = __shfl((int)A0, srcA), a1 = __shfl((int)A1, srcA); \
            int a2 = __shfl((int)A0, srcB), a3 = __shfl((int)A1, srcB); \
            int b0 = __shfl((int)B0, srcA), b1 = __shfl((int)B1, srcA); \
            int b2 = __shfl((int)B0, srcB), b3 = __shfl((int)B1, srcB); \
            v4i w; \
            w.x = hig ? b0 : a0; w.y = hig ? b1 : a1; \
            w.z = hig ? b2 : a2; w.w = hig ? b3 : a3; \
            v8s pf = __builtin_bit_cast(v8s, w); \
            __builtin_amdgcn_s_setprio(1); \
            _Pragma("unroll") \
            for (int dt = 0; dt < 4; dt++) \
                o_[qt][dt] = MFMA16(vf[dt], pf, o_[qt][dt]); \
            __builtin_amdgcn_s_setprio(0); \
        } }

    // ---- main loop: 16 tiles of 64 k-rows, LDS double-buffered -----------
    int cur = 0;
    STAGE(0, 0);
    __syncthreads();
    #pragma unroll 1
    for (int t = 0; t < 16; t++) {
        if (t < 15) STAGE(cur ^ 1, (t + 1) * 64);   // async, lands by barrier
        COMPUTE_LDS(cur, 0);
        COMPUTE_LDS(cur, 1);
        __syncthreads();    // drains vmcnt: next buffer ready; reads of cur done
        cur ^= 1;
    }

    // ---- epilogue: reduce per-lane l across lane-groups once, write attT ----
    #pragma unroll
    for (int qt = 0; qt < 4; qt++) {
        float l = l_[qt];
        l += __shfl_xor(l, 16);
        l += __shfl_xor(l, 32);
        float invl = 1.0f / l;
        ushort* at = attT + ((size_t)(b * NPIX + q0 + qt * 16 + col)) * HIDDEN + h * DIMH;
        #pragma unroll
        for (int dt = 0; dt < 4; dt++) {
            uint2 uu;
            uu.x = pkbf(o_[qt][dt][0] * invl, o_[qt][dt][1] * invl);
            uu.y = pkbf(o_[qt][dt][2] * invl, o_[qt][dt][3] * invl);
            *(uint2*)(at + dt * 16 + 4 * lg) = uu;
        }
    }
    #undef STAGE
    #undef COMPUTE_LDS
}

// ---------------------------------------------------------------------------
// Kernel 4: out-proj GEMM with global_load_lds staging (R15-proven).
// ---------------------------------------------------------------------------
__global__ __launch_bounds__(256) void gemm_out_mfma(
    const ushort* __restrict__ Wo,
    const ushort* __restrict__ attT,
    const float* __restrict__ x, float* __restrict__ out)
{
    int b = blockIdx.z;
    int o0 = blockIdx.y * 128;
    int p0 = blockIdx.x * 128;
    int tid = threadIdx.x;
    int wave = tid >> 6, lane = tid & 63;
    int wy = wave >> 1, wx = wave & 1;
    int col = lane & 15, lg = lane >> 4;
    int ow = o0 + wy * 64, pw = p0 + wx * 64;

    __shared__ __align__(16) ushort sAa[128 * 64];  // attT rows
    __shared__ __align__(16) ushort sBb[128 * 64];  // Wo rows

    int rIn = lane >> 3;
    int chS = (lane & 7) ^ rIn;
    int rowStage = wave * 32 + rIn;
    const ushort* gA = attT + ((size_t)b * NPIX + p0 + rowStage) * HIDDEN + chS * 8;
    const ushort* gB = Wo + (size_t)(o0 + rowStage) * HIDDEN + chS * 8;

    v4f acc[4][4];   // [pt][ot]
    #pragma unroll
    for (int i = 0; i < 4; i++)
        #pragma unroll
        for (int j = 0; j < 4; j++) acc[i][j] = (v4f){0.f, 0.f, 0.f, 0.f};

    int rowA = wx * 64 + col;   // p side
    int rowB = wy * 64 + col;   // o side
    int c7 = col & 7;

    #pragma unroll 1
    for (int c0 = 0; c0 < HIDDEN; c0 += 64) {
        #pragma unroll
        for (int j = 0; j < 4; j++) {
            gload16(gA + (size_t)j * 8 * HIDDEN + c0, &sAa[(wave * 4 + j) * 512]);
            gload16(gB + (size_t)j * 8 * HIDDEN + c0, &sBb[(wave * 4 + j) * 512]);
        }
        __syncthreads();
        #pragma unroll
        for (int hh = 0; hh < 2; hh++) {
            int ch = (hh * 4 + lg) ^ c7;
            v8s af[4], bf[4];
            #pragma unroll
            for (int i = 0; i < 4; i++) {
                af[i] = *(const v8s*)&sAa[(rowA + i * 16) * 64 + ch * 8];
                bf[i] = *(const v8s*)&sBb[(rowB + i * 16) * 64 + ch * 8];
            }
            #pragma unroll
            for (int i = 0; i < 4; i++)
                #pragma unroll
                for (int j = 0; j < 4; j++)
                    acc[i][j] = MFMA16(af[i], bf[j], acc[i][j]);
        }
        __syncthreads();
    }

    const float INV_DEN = 1.3130643285972254f;
    #pragma unroll
    for (int pt = 0; pt < 4; pt++) {
        #pragma unroll
        for (int ot = 0; ot < 4; ot++) {
            size_t base = ((size_t)b * HIDDEN + ow + ot * 16 + col) * NPIX
                        + pw + pt * 16 + 4 * lg;
            float4 res = *(const float4*)&x[base];
            float4 y;
            y.x = (acc[pt][ot][0] * 0.7f + res.x * 0.3f) * INV_DEN;
            y.y = (acc[pt][ot][1] * 0.7f + res.y * 0.3f) * INV_DEN;
            y.z = (acc[pt][ot][2] * 0.7f + res.z * 0.3f) * INV_DEN;
            y.w = (acc[pt][ot][3] * 0.7f + res.w * 0.3f) * INV_DEN;
            *(float4*)&out[base] = y;
        }
    }
}

// ---------------------------------------------------------------------------
extern "C" void kernel_launch(void* const* d_in, const int* in_sizes, int n_in,
                              void* d_out, int out_size, void* d_ws, size_t ws_size,
                              hipStream_t stream)
{
    const float* x      = (const float*)d_in[0];
    const float* w_qkv  = (const float*)d_in[1];
    const float* w_out  = (const float*)d_in[2];
    const float* mem_kv = (const float*)d_in[3];
    float* out = (float*)d_out;

    char* ws = (char*)d_ws;
    ushort* wnB = (ushort*)ws; ws += (size_t)2048 * CIN * 2;
    ushort* Xt  = (ushort*)ws; ws += (size_t)BATCH * NPIX * CIN * 2;
    ushort* Qb  = (ushort*)ws; ws += (size_t)BATCH * HEADS * NPIX * DIMH * 2;
    ushort* Kb  = (ushort*)ws; ws += (size_t)BATCH * HEADS * NPIX * DIMH * 2;
    ushort* Vb  = (ushort*)ws; ws += (size_t)BATCH * HEADS * NPIX * DIMH * 2;
    ushort* attT = (ushort*)ws; ws += (size_t)BATCH * NPIX * HIDDEN * 2;
    float* qsA = (float*)ws;  ws += (size_t)BATCH * HEADS * NPIX * 4;
    float* msk = (float*)ws;  ws += 8 * 16 * 4;
    __hip_bfloat16* mk = (__hip_bfloat16*)ws; ws += (size_t)8 * 16 * 64 * 2;
    __hip_bfloat16* mv = (__hip_bfloat16*)ws; ws += (size_t)8 * 64 * 32 * 2;

    prep_fused<<<4104, 256, 0, stream>>>(
        x, w_qkv, w_out, mem_kv, Xt, wnB, mk, mv, msk);

    gemm_qkv_mfma<<<1536, 256, 0, stream>>>(
        wnB, Xt, Qb, Kb, Vb, qsA);

    attn_mfma_kernel<<<512, 256, 0, stream>>>(
        (const __hip_bfloat16*)Qb, (const __hip_bfloat16*)Kb,
        (const __hip_bfloat16*)Vb, qsA, mk, mv, msk, attT);

    gemm_out_mfma<<<dim3(8, 4, BATCH), 256, 0, stream>>>(
        wnB + (size_t)OQKV * CIN, attT, x, out);
}